// Round 1
// baseline (1685.281 us; speedup 1.0000x reference)
//
#include <hip/hip_runtime.h>
#include <cstdint>
#include <cmath>

#define NLEV 16
#define TBL (1u << 19)

struct LevelParams {
    float scale[NLEV];
    uint32_t res[NLEV];
    uint32_t hashed_mask;
};

// ---------------------------------------------------------------------------
// Prep: weight-norm both layers; transpose W1 to [35][64] so per-feature
// columns are contiguous (enables s_load_dwordx16 batches in the main kernel).
// ws layout: w1t[35*64] | w2n[13*64]
// ---------------------------------------------------------------------------
__global__ __launch_bounds__(128) void prep_weights(
    const float* __restrict__ v1, const float* __restrict__ g1,
    const float* __restrict__ v2, const float* __restrict__ g2,
    float* __restrict__ w1t, float* __restrict__ w2n)
{
    int t = threadIdx.x;
    if (t < 64) {
        float s = 0.f;
        #pragma unroll
        for (int k = 0; k < 35; ++k) { float v = v1[t*35 + k]; s += v*v; }
        float f = g1[t] / sqrtf(s);
        #pragma unroll
        for (int k = 0; k < 35; ++k) w1t[k*64 + t] = v1[t*35 + k] * f;
    } else if (t < 77) {
        int r = t - 64;
        float s = 0.f;
        #pragma unroll
        for (int k = 0; k < 64; ++k) { float v = v2[r*64 + k]; s += v*v; }
        float f = g2[r] / sqrtf(s);
        #pragma unroll
        for (int k = 0; k < 64; ++k) w2n[r*64 + k] = v2[r*64 + k] * f;
    }
}

// ---------------------------------------------------------------------------
// Fused: hashgrid encode + MLP, one thread per point.
// Encoding features are folded straight into the 64 layer-1 pre-activations,
// so no runtime-indexed per-thread array exists (avoids scratch).
// All weight loads are wave-uniform -> scalar loads + SGPR-operand FMAs.
// ---------------------------------------------------------------------------
__global__ __launch_bounds__(256) void sdf_fused(
    const float* __restrict__ x,
    const float* __restrict__ table,
    const float* __restrict__ w1t,   // [35][64] transposed, weight-normed
    const float* __restrict__ b1,    // [64]
    const float* __restrict__ w2,    // [13][64] weight-normed
    const float* __restrict__ b2,    // [13]
    float* __restrict__ out, int N, LevelParams P)
{
    int i = blockIdx.x * 256 + threadIdx.x;
    bool valid = (i < N);
    int ii = valid ? i : (N - 1);

    float x0 = x[3*(size_t)ii + 0];
    float x1 = x[3*(size_t)ii + 1];
    float x2 = x[3*(size_t)ii + 2];
    float u0 = fminf(fmaxf(x0 + 0.5f, 0.f), 1.f);
    float u1 = fminf(fmaxf(x1 + 0.5f, 0.f), 1.f);
    float u2 = fminf(fmaxf(x2 + 0.5f, 0.f), 1.f);

    // layer-1 pre-activations, seeded with bias + xyz part
    float h[64];
    #pragma unroll
    for (int j = 0; j < 64; ++j) {
        h[j] = b1[j] + x0 * w1t[0*64 + j] + x1 * w1t[1*64 + j] + x2 * w1t[2*64 + j];
    }

    for (int l = 0; l < NLEV; ++l) {
        float s = P.scale[l];
        uint32_t res = P.res[l];
        bool hashed = (P.hashed_mask >> l) & 1u;

        float px = u0 * s + 0.5f;
        float py = u1 * s + 0.5f;
        float pz = u2 * s + 0.5f;
        float fx = floorf(px), fy = floorf(py), fz = floorf(pz);
        float wx1 = px - fx, wy1 = py - fy, wz1 = pz - fz;
        float wx0 = 1.f - wx1, wy0 = 1.f - wy1, wz0 = 1.f - wz1;
        uint32_t cx = (uint32_t)fx, cy = (uint32_t)fy, cz = (uint32_t)fz;

        uint32_t ix0, ix1, iy0, iy1, iz0, iz1;
        if (hashed) {
            ix0 = cx;                 ix1 = cx + 1u;
            iy0 = cy * 2654435761u;   iy1 = (cy + 1u) * 2654435761u;
            iz0 = cz * 805459861u;    iz1 = (cz + 1u) * 805459861u;
        } else {
            ix0 = cx;                 ix1 = cx + 1u;
            iy0 = cy * res;           iy1 = iy0 + res;
            uint32_t rr = res * res;
            iz0 = cz * rr;            iz1 = iz0 + rr;
        }
        float wxy00 = wx0*wy0, wxy10 = wx1*wy0, wxy01 = wx0*wy1, wxy11 = wx1*wy1;

        const float* tl = table + (size_t)l * (size_t)(TBL * 2u);
        float a0 = 0.f, a1 = 0.f;
        #pragma unroll
        for (int c = 0; c < 8; ++c) {
            uint32_t jx = (c & 1) ? ix1 : ix0;
            uint32_t jy = (c & 2) ? iy1 : iy0;
            uint32_t jz = (c & 4) ? iz1 : iz0;
            uint32_t idx = hashed ? ((jx ^ jy ^ jz) & (TBL - 1u))
                                  : (jx + jy + jz);           // dense idx < TBL always
            float wxy = (c & 2) ? ((c & 1) ? wxy11 : wxy01)
                                : ((c & 1) ? wxy10 : wxy00);
            float w = wxy * ((c & 4) ? wz1 : wz0);
            const float2 v = *reinterpret_cast<const float2*>(tl + (size_t)idx * 2u);
            a0 += w * v.x;
            a1 += w * v.y;
        }

        // fold this level's 2 features into the layer-1 pre-activations
        const float* c0p = w1t + (3 + 2*l) * 64;
        const float* c1p = c0p + 64;
        #pragma unroll
        for (int j = 0; j < 64; ++j) {
            h[j] += a0 * c0p[j] + a1 * c1p[j];
        }
    }

    // softplus(100*x)/100, numerically stable (logaddexp form)
    #pragma unroll
    for (int j = 0; j < 64; ++j) {
        float z = 100.f * h[j];
        float t = __expf(-fabsf(z));
        h[j] = (fmaxf(z, 0.f) + __logf(1.f + t)) * 0.01f;
    }

    // layer 2: 13 outputs
    float* op = out + (size_t)ii * 13;
    for (int o = 0; o < 13; ++o) {
        float a = b2[o];
        const float* wr = w2 + o * 64;
        #pragma unroll
        for (int k = 0; k < 64; ++k) a += h[k] * wr[k];
        if (valid) op[o] = a;
    }
}

extern "C" void kernel_launch(void* const* d_in, const int* in_sizes, int n_in,
                              void* d_out, int out_size, void* d_ws, size_t ws_size,
                              hipStream_t stream)
{
    const float* x     = (const float*)d_in[0];
    const float* table = (const float*)d_in[1];
    const float* v1    = (const float*)d_in[2];
    const float* g1    = (const float*)d_in[3];
    const float* b1    = (const float*)d_in[4];
    const float* v2    = (const float*)d_in[5];
    const float* g2    = (const float*)d_in[6];
    const float* b2    = (const float*)d_in[7];
    float* out = (float*)d_out;
    int N = in_sizes[0] / 3;

    float* w1t = (float*)d_ws;          // 35*64 floats
    float* w2n = w1t + 35 * 64;         // 13*64 floats

    LevelParams P;
    P.hashed_mask = 0u;
    double pls = pow(128.0, 1.0 / 15.0);   // PER_LEVEL_SCALE, matches python
    for (int l = 0; l < NLEV; ++l) {
        double sc = 16.0 * pow(pls, (double)l) - 1.0;
        P.scale[l] = (float)sc;
        uint32_t res = (uint32_t)(ceil(sc)) + 1u;
        P.res[l] = res;
        uint64_t r3 = (uint64_t)res * res * res;
        if (r3 > (uint64_t)TBL) P.hashed_mask |= (1u << l);
    }

    prep_weights<<<1, 128, 0, stream>>>(v1, g1, v2, g2, w1t, w2n);

    int blocks = (N + 255) / 256;
    sdf_fused<<<blocks, 256, 0, stream>>>(x, table, w1t, b1, w2n, b2, out, N, P);
}

// Round 2
// 1478.345 us; speedup vs baseline: 1.1400x; 1.1400x over previous
//
#include <hip/hip_runtime.h>
#include <hip/hip_fp16.h>
#include <cstdint>
#include <cmath>

#define NLEV 16
#define TBL (1u << 19)

struct LevelParams {
    float scale[NLEV];
    uint32_t res[NLEV];
    uint32_t hashed_mask;
};

// ---------------------------------------------------------------------------
// Prep 1: weight-norm both layers; transpose W1 to [35][64].
// ---------------------------------------------------------------------------
__global__ __launch_bounds__(128) void prep_weights(
    const float* __restrict__ v1, const float* __restrict__ g1,
    const float* __restrict__ v2, const float* __restrict__ g2,
    float* __restrict__ w1t, float* __restrict__ w2n)
{
    int t = threadIdx.x;
    if (t < 64) {
        float s = 0.f;
        #pragma unroll
        for (int k = 0; k < 35; ++k) { float v = v1[t*35 + k]; s += v*v; }
        float f = g1[t] / sqrtf(s);
        #pragma unroll
        for (int k = 0; k < 35; ++k) w1t[k*64 + t] = v1[t*35 + k] * f;
    } else if (t < 77) {
        int r = t - 64;
        float s = 0.f;
        #pragma unroll
        for (int k = 0; k < 64; ++k) { float v = v2[r*64 + k]; s += v*v; }
        float f = g2[r] / sqrtf(s);
        #pragma unroll
        for (int k = 0; k < 64; ++k) w2n[r*64 + k] = v2[r*64 + k] * f;
    }
}

// ---------------------------------------------------------------------------
// Prep 2: pack fp32 table [16*T][2] -> fp16x2 (one dword per entry).
// Halves the gathered footprint: 2 MB/level fits in each XCD's 4 MB L2.
// ---------------------------------------------------------------------------
__global__ __launch_bounds__(256) void pack_table(
    const float2* __restrict__ in, uint32_t* __restrict__ out, int n)
{
    int i = blockIdx.x * 256 + threadIdx.x;
    if (i < n) {
        float2 v = in[i];
        __half2 h = __floats2half2_rn(v.x, v.y);
        out[i] = *reinterpret_cast<uint32_t*>(&h);
    }
}

// ---------------------------------------------------------------------------
// Fused encode + MLP. PACKED=1 gathers fp16x2 dwords from ws; PACKED=0 is the
// fp32 fallback (ws too small). One thread per point; encoding features fold
// straight into the 64 layer-1 pre-activations (no runtime-indexed arrays).
// ---------------------------------------------------------------------------
template <int PACKED>
__global__ __launch_bounds__(256) void sdf_fused(
    const float* __restrict__ x,
    const void* __restrict__ table,  // PACKED: uint32_t[16*T]; else float[16*T*2]
    const float* __restrict__ w1t,   // [35][64] transposed, weight-normed
    const float* __restrict__ b1,    // [64]
    const float* __restrict__ w2,    // [13][64] weight-normed
    const float* __restrict__ b2,    // [13]
    float* __restrict__ out, int N, LevelParams P)
{
    int i = blockIdx.x * 256 + threadIdx.x;
    bool valid = (i < N);
    int ii = valid ? i : (N - 1);

    float x0 = x[3*(size_t)ii + 0];
    float x1 = x[3*(size_t)ii + 1];
    float x2 = x[3*(size_t)ii + 2];
    float u0 = fminf(fmaxf(x0 + 0.5f, 0.f), 1.f);
    float u1 = fminf(fmaxf(x1 + 0.5f, 0.f), 1.f);
    float u2 = fminf(fmaxf(x2 + 0.5f, 0.f), 1.f);

    float h[64];
    #pragma unroll
    for (int j = 0; j < 64; ++j) {
        h[j] = b1[j] + x0 * w1t[0*64 + j] + x1 * w1t[1*64 + j] + x2 * w1t[2*64 + j];
    }

    for (int l = 0; l < NLEV; ++l) {
        float s = P.scale[l];
        uint32_t res = P.res[l];
        bool hashed = (P.hashed_mask >> l) & 1u;

        float px = u0 * s + 0.5f;
        float py = u1 * s + 0.5f;
        float pz = u2 * s + 0.5f;
        float fx = floorf(px), fy = floorf(py), fz = floorf(pz);
        float wx1 = px - fx, wy1 = py - fy, wz1 = pz - fz;
        float wx0 = 1.f - wx1, wy0 = 1.f - wy1, wz0 = 1.f - wz1;
        uint32_t cx = (uint32_t)fx, cy = (uint32_t)fy, cz = (uint32_t)fz;

        uint32_t ix0, ix1, iy0, iy1, iz0, iz1;
        if (hashed) {
            ix0 = cx;                 ix1 = cx + 1u;
            iy0 = cy * 2654435761u;   iy1 = (cy + 1u) * 2654435761u;
            iz0 = cz * 805459861u;    iz1 = (cz + 1u) * 805459861u;
        } else {
            ix0 = cx;                 ix1 = cx + 1u;
            iy0 = cy * res;           iy1 = iy0 + res;
            uint32_t rr = res * res;
            iz0 = cz * rr;            iz1 = iz0 + rr;
        }

        // all 8 corner indices, then all 8 gathers in flight, then the fold
        uint32_t idxs[8];
        #pragma unroll
        for (int c = 0; c < 8; ++c) {
            uint32_t jx = (c & 1) ? ix1 : ix0;
            uint32_t jy = (c & 2) ? iy1 : iy0;
            uint32_t jz = (c & 4) ? iz1 : iz0;
            idxs[c] = hashed ? ((jx ^ jy ^ jz) & (TBL - 1u)) : (jx + jy + jz);
        }

        float2 vals[8];
        if (PACKED) {
            const uint32_t* tl = (const uint32_t*)table + (size_t)l * TBL;
            uint32_t raw[8];
            #pragma unroll
            for (int c = 0; c < 8; ++c) raw[c] = tl[idxs[c]];
            #pragma unroll
            for (int c = 0; c < 8; ++c) {
                __half2 hv = *reinterpret_cast<__half2*>(&raw[c]);
                vals[c] = __half22float2(hv);
            }
        } else {
            const float* tl = (const float*)table + (size_t)l * (size_t)(TBL * 2u);
            #pragma unroll
            for (int c = 0; c < 8; ++c) {
                vals[c] = *reinterpret_cast<const float2*>(tl + (size_t)idxs[c] * 2u);
            }
        }

        float wxy00 = wx0*wy0, wxy10 = wx1*wy0, wxy01 = wx0*wy1, wxy11 = wx1*wy1;
        float a0 = 0.f, a1 = 0.f;
        #pragma unroll
        for (int c = 0; c < 8; ++c) {
            float wxy = (c & 2) ? ((c & 1) ? wxy11 : wxy01)
                                : ((c & 1) ? wxy10 : wxy00);
            float w = wxy * ((c & 4) ? wz1 : wz0);
            a0 += w * vals[c].x;
            a1 += w * vals[c].y;
        }

        const float* c0p = w1t + (3 + 2*l) * 64;
        const float* c1p = c0p + 64;
        #pragma unroll
        for (int j = 0; j < 64; ++j) {
            h[j] += a0 * c0p[j] + a1 * c1p[j];
        }
    }

    // softplus(100*x)/100, numerically stable
    #pragma unroll
    for (int j = 0; j < 64; ++j) {
        float z = 100.f * h[j];
        float t = __expf(-fabsf(z));
        h[j] = (fmaxf(z, 0.f) + __logf(1.f + t)) * 0.01f;
    }

    float* op = out + (size_t)ii * 13;
    for (int o = 0; o < 13; ++o) {
        float a = b2[o];
        const float* wr = w2 + o * 64;
        #pragma unroll
        for (int k = 0; k < 64; ++k) a += h[k] * wr[k];
        if (valid) op[o] = a;
    }
}

extern "C" void kernel_launch(void* const* d_in, const int* in_sizes, int n_in,
                              void* d_out, int out_size, void* d_ws, size_t ws_size,
                              hipStream_t stream)
{
    const float* x     = (const float*)d_in[0];
    const float* table = (const float*)d_in[1];
    const float* v1    = (const float*)d_in[2];
    const float* g1    = (const float*)d_in[3];
    const float* b1    = (const float*)d_in[4];
    const float* v2    = (const float*)d_in[5];
    const float* g2    = (const float*)d_in[6];
    const float* b2    = (const float*)d_in[7];
    float* out = (float*)d_out;
    int N = in_sizes[0] / 3;

    const int n_entries = NLEV * (int)TBL;               // 8.4M entries
    const size_t packed_bytes = (size_t)n_entries * 4u;  // 32 MB
    const size_t w_bytes = (35*64 + 13*64) * sizeof(float);
    bool packed_ok = (ws_size >= packed_bytes + w_bytes);

    uint32_t* tpk = (uint32_t*)d_ws;                     // 32 MB packed table
    float* w1t = (float*)((char*)d_ws + (packed_ok ? packed_bytes : 0));
    float* w2n = w1t + 35 * 64;

    LevelParams P;
    P.hashed_mask = 0u;
    double pls = pow(128.0, 1.0 / 15.0);   // PER_LEVEL_SCALE
    for (int l = 0; l < NLEV; ++l) {
        double sc = 16.0 * pow(pls, (double)l) - 1.0;
        P.scale[l] = (float)sc;
        uint32_t res = (uint32_t)(ceil(sc)) + 1u;
        P.res[l] = res;
        uint64_t r3 = (uint64_t)res * res * res;
        if (r3 > (uint64_t)TBL) P.hashed_mask |= (1u << l);
    }

    prep_weights<<<1, 128, 0, stream>>>(v1, g1, v2, g2, w1t, w2n);

    int blocks = (N + 255) / 256;
    if (packed_ok) {
        pack_table<<<(n_entries + 255) / 256, 256, 0, stream>>>(
            (const float2*)table, tpk, n_entries);
        sdf_fused<1><<<blocks, 256, 0, stream>>>(
            x, (const void*)tpk, w1t, b1, w2n, b2, out, N, P);
    } else {
        sdf_fused<0><<<blocks, 256, 0, stream>>>(
            x, (const void*)table, w1t, b1, w2n, b2, out, N, P);
    }
}

// Round 3
// 1019.210 us; speedup vs baseline: 1.6535x; 1.4505x over previous
//
#include <hip/hip_runtime.h>
#include <hip/hip_fp16.h>
#include <cstdint>
#include <cmath>

#define NLEV 16
#define TBL (1u << 19)

struct LevelParams {
    float scale[NLEV];
    uint32_t res[NLEV];
    uint32_t hashed_mask;
};

// ---------------------------------------------------------------------------
// Prep 1: weight-norm both layers; transpose W1 to [35][64].
// ---------------------------------------------------------------------------
__global__ __launch_bounds__(128) void prep_weights(
    const float* __restrict__ v1, const float* __restrict__ g1,
    const float* __restrict__ v2, const float* __restrict__ g2,
    float* __restrict__ w1t, float* __restrict__ w2n)
{
    int t = threadIdx.x;
    if (t < 64) {
        float s = 0.f;
        #pragma unroll
        for (int k = 0; k < 35; ++k) { float v = v1[t*35 + k]; s += v*v; }
        float f = g1[t] / sqrtf(s);
        #pragma unroll
        for (int k = 0; k < 35; ++k) w1t[k*64 + t] = v1[t*35 + k] * f;
    } else if (t < 77) {
        int r = t - 64;
        float s = 0.f;
        #pragma unroll
        for (int k = 0; k < 64; ++k) { float v = v2[r*64 + k]; s += v*v; }
        float f = g2[r] / sqrtf(s);
        #pragma unroll
        for (int k = 0; k < 64; ++k) w2n[r*64 + k] = v2[r*64 + k] * f;
    }
}

// ---------------------------------------------------------------------------
// Prep 2: pack fp32 table [16*T][2] -> fp16x2 (one dword per entry).
// ---------------------------------------------------------------------------
__global__ __launch_bounds__(256) void pack_table(
    const float2* __restrict__ in, uint32_t* __restrict__ out, int n)
{
    int i = blockIdx.x * 256 + threadIdx.x;
    if (i < n) {
        float2 v = in[i];
        __half2 h = __floats2half2_rn(v.x, v.y);
        out[i] = *reinterpret_cast<uint32_t*>(&h);
    }
}

// ---------------------------------------------------------------------------
// Device helper: trilinear hashgrid lookup for one (point, level).
// ---------------------------------------------------------------------------
__device__ __forceinline__ void encode_one(
    float u0, float u1, float u2, float s, uint32_t res, bool hashed,
    const uint32_t* __restrict__ tl, float& a0, float& a1)
{
    float px = u0 * s + 0.5f;
    float py = u1 * s + 0.5f;
    float pz = u2 * s + 0.5f;
    float fx = floorf(px), fy = floorf(py), fz = floorf(pz);
    float wx1 = px - fx, wy1 = py - fy, wz1 = pz - fz;
    float wx0 = 1.f - wx1, wy0 = 1.f - wy1, wz0 = 1.f - wz1;
    uint32_t cx = (uint32_t)fx, cy = (uint32_t)fy, cz = (uint32_t)fz;

    uint32_t ix0, ix1, iy0, iy1, iz0, iz1;
    if (hashed) {
        ix0 = cx;                 ix1 = cx + 1u;
        iy0 = cy * 2654435761u;   iy1 = (cy + 1u) * 2654435761u;
        iz0 = cz * 805459861u;    iz1 = (cz + 1u) * 805459861u;
    } else {
        ix0 = cx;                 ix1 = cx + 1u;
        iy0 = cy * res;           iy1 = iy0 + res;
        uint32_t rr = res * res;
        iz0 = cz * rr;            iz1 = iz0 + rr;
    }

    uint32_t idxs[8];
    #pragma unroll
    for (int c = 0; c < 8; ++c) {
        uint32_t jx = (c & 1) ? ix1 : ix0;
        uint32_t jy = (c & 2) ? iy1 : iy0;
        uint32_t jz = (c & 4) ? iz1 : iz0;
        idxs[c] = hashed ? ((jx ^ jy ^ jz) & (TBL - 1u)) : (jx + jy + jz);
    }
    uint32_t raw[8];
    #pragma unroll
    for (int c = 0; c < 8; ++c) raw[c] = tl[idxs[c]];

    float wxy00 = wx0*wy0, wxy10 = wx1*wy0, wxy01 = wx0*wy1, wxy11 = wx1*wy1;
    a0 = 0.f; a1 = 0.f;
    #pragma unroll
    for (int c = 0; c < 8; ++c) {
        float wxy = (c & 2) ? ((c & 1) ? wxy11 : wxy01)
                            : ((c & 1) ? wxy10 : wxy00);
        float w = wxy * ((c & 4) ? wz1 : wz0);
        __half2 hv = *reinterpret_cast<__half2*>(&raw[c]);
        float2 v = __half22float2(hv);
        a0 += w * v.x;
        a1 += w * v.y;
    }
}

// ---------------------------------------------------------------------------
// Pass A: level-partitioned encode. Blocks are level-major, so the live
// level's 2 MB table stays L2-resident per XCD. Writes half2 features.
// ---------------------------------------------------------------------------
__global__ __launch_bounds__(256) void encode_level(
    const float* __restrict__ x, const uint32_t* __restrict__ tpk,
    uint32_t* __restrict__ feats, int N, int chunks_per_level, LevelParams P)
{
    int bid = blockIdx.x;
    int l = bid / chunks_per_level;
    int p = (bid - l * chunks_per_level) * 256 + threadIdx.x;
    if (p >= N) return;

    float x0 = x[3*(size_t)p + 0];
    float x1 = x[3*(size_t)p + 1];
    float x2 = x[3*(size_t)p + 2];
    float u0 = fminf(fmaxf(x0 + 0.5f, 0.f), 1.f);
    float u1 = fminf(fmaxf(x1 + 0.5f, 0.f), 1.f);
    float u2 = fminf(fmaxf(x2 + 0.5f, 0.f), 1.f);

    bool hashed = (P.hashed_mask >> l) & 1u;
    const uint32_t* tl = tpk + (size_t)l * TBL;
    float a0, a1;
    encode_one(u0, u1, u2, P.scale[l], P.res[l], hashed, tl, a0, a1);

    __half2 hv = __floats2half2_rn(a0, a1);
    feats[(size_t)l * N + p] = *reinterpret_cast<uint32_t*>(&hv);
}

// ---------------------------------------------------------------------------
// Pass B: MLP 35 -> 64 (softplus beta=100) -> 13. Weights wave-uniform.
// ---------------------------------------------------------------------------
__global__ __launch_bounds__(256) void mlp_kernel(
    const float* __restrict__ x, const uint32_t* __restrict__ feats,
    const float* __restrict__ w1t,   // [35][64]
    const float* __restrict__ b1,    // [64]
    const float* __restrict__ w2,    // [13][64]
    const float* __restrict__ b2,    // [13]
    float* __restrict__ out, int N)
{
    int p = blockIdx.x * 256 + threadIdx.x;
    bool valid = (p < N);
    int pp = valid ? p : (N - 1);

    float in[35];
    in[0] = x[3*(size_t)pp + 0];
    in[1] = x[3*(size_t)pp + 1];
    in[2] = x[3*(size_t)pp + 2];

    uint32_t rf[NLEV];
    #pragma unroll
    for (int l = 0; l < NLEV; ++l) rf[l] = feats[(size_t)l * N + pp];
    #pragma unroll
    for (int l = 0; l < NLEV; ++l) {
        __half2 hv = *reinterpret_cast<__half2*>(&rf[l]);
        float2 f = __half22float2(hv);
        in[3 + 2*l] = f.x;
        in[4 + 2*l] = f.y;
    }

    float h[64];
    #pragma unroll
    for (int j = 0; j < 64; ++j) h[j] = b1[j];
    #pragma unroll
    for (int k = 0; k < 35; ++k) {
        float v = in[k];
        #pragma unroll
        for (int j = 0; j < 64; ++j) h[j] = fmaf(v, w1t[k*64 + j], h[j]);
    }

    #pragma unroll
    for (int j = 0; j < 64; ++j) {
        float z = 100.f * h[j];
        float t = __expf(-fabsf(z));
        h[j] = (fmaxf(z, 0.f) + __logf(1.f + t)) * 0.01f;
    }

    float* op = out + (size_t)pp * 13;
    for (int o = 0; o < 13; ++o) {
        float a = b2[o];
        const float* wr = w2 + o * 64;
        #pragma unroll
        for (int k = 0; k < 64; ++k) a = fmaf(h[k], wr[k], a);
        if (valid) op[o] = a;
    }
}

// ---------------------------------------------------------------------------
// Fallback: round-2 fused kernel (used if ws can't hold table+features).
// ---------------------------------------------------------------------------
template <int PACKED>
__global__ __launch_bounds__(256) void sdf_fused(
    const float* __restrict__ x, const void* __restrict__ table,
    const float* __restrict__ w1t, const float* __restrict__ b1,
    const float* __restrict__ w2, const float* __restrict__ b2,
    float* __restrict__ out, int N, LevelParams P)
{
    int i = blockIdx.x * 256 + threadIdx.x;
    bool valid = (i < N);
    int ii = valid ? i : (N - 1);

    float x0 = x[3*(size_t)ii + 0];
    float x1 = x[3*(size_t)ii + 1];
    float x2 = x[3*(size_t)ii + 2];
    float u0 = fminf(fmaxf(x0 + 0.5f, 0.f), 1.f);
    float u1 = fminf(fmaxf(x1 + 0.5f, 0.f), 1.f);
    float u2 = fminf(fmaxf(x2 + 0.5f, 0.f), 1.f);

    float h[64];
    #pragma unroll
    for (int j = 0; j < 64; ++j) {
        h[j] = b1[j] + x0 * w1t[0*64 + j] + x1 * w1t[1*64 + j] + x2 * w1t[2*64 + j];
    }

    for (int l = 0; l < NLEV; ++l) {
        bool hashed = (P.hashed_mask >> l) & 1u;
        float a0, a1;
        if (PACKED) {
            const uint32_t* tl = (const uint32_t*)table + (size_t)l * TBL;
            encode_one(u0, u1, u2, P.scale[l], P.res[l], hashed, tl, a0, a1);
        } else {
            // fp32 path (slow, correctness fallback)
            const float* tl = (const float*)table + (size_t)l * (size_t)(TBL * 2u);
            float s = P.scale[l]; uint32_t res = P.res[l];
            float px = u0*s + 0.5f, py = u1*s + 0.5f, pz = u2*s + 0.5f;
            float fx = floorf(px), fy = floorf(py), fz = floorf(pz);
            float wx1 = px-fx, wy1 = py-fy, wz1 = pz-fz;
            float wx0 = 1.f-wx1, wy0 = 1.f-wy1, wz0 = 1.f-wz1;
            uint32_t cx = (uint32_t)fx, cy = (uint32_t)fy, cz = (uint32_t)fz;
            a0 = 0.f; a1 = 0.f;
            #pragma unroll
            for (int c = 0; c < 8; ++c) {
                uint32_t jx = cx + (c & 1);
                uint32_t jy = cy + ((c >> 1) & 1);
                uint32_t jz = cz + ((c >> 2) & 1);
                uint32_t idx = hashed
                    ? ((jx ^ (jy * 2654435761u) ^ (jz * 805459861u)) & (TBL - 1u))
                    : (jx + jy * res + jz * res * res);
                float w = ((c & 1) ? wx1 : wx0) * ((c & 2) ? wy1 : wy0)
                        * ((c & 4) ? wz1 : wz0);
                float2 v = *reinterpret_cast<const float2*>(tl + (size_t)idx * 2u);
                a0 += w * v.x; a1 += w * v.y;
            }
        }
        const float* c0p = w1t + (3 + 2*l) * 64;
        const float* c1p = c0p + 64;
        #pragma unroll
        for (int j = 0; j < 64; ++j) h[j] += a0 * c0p[j] + a1 * c1p[j];
    }

    #pragma unroll
    for (int j = 0; j < 64; ++j) {
        float z = 100.f * h[j];
        float t = __expf(-fabsf(z));
        h[j] = (fmaxf(z, 0.f) + __logf(1.f + t)) * 0.01f;
    }

    float* op = out + (size_t)ii * 13;
    for (int o = 0; o < 13; ++o) {
        float a = b2[o];
        const float* wr = w2 + o * 64;
        #pragma unroll
        for (int k = 0; k < 64; ++k) a += h[k] * wr[k];
        if (valid) op[o] = a;
    }
}

extern "C" void kernel_launch(void* const* d_in, const int* in_sizes, int n_in,
                              void* d_out, int out_size, void* d_ws, size_t ws_size,
                              hipStream_t stream)
{
    const float* x     = (const float*)d_in[0];
    const float* table = (const float*)d_in[1];
    const float* v1    = (const float*)d_in[2];
    const float* g1    = (const float*)d_in[3];
    const float* b1    = (const float*)d_in[4];
    const float* v2    = (const float*)d_in[5];
    const float* g2    = (const float*)d_in[6];
    const float* b2    = (const float*)d_in[7];
    float* out = (float*)d_out;
    int N = in_sizes[0] / 3;

    const int n_entries = NLEV * (int)TBL;
    const size_t packed_bytes = (size_t)n_entries * 4u;          // 32 MB
    const size_t feats_bytes  = (size_t)NLEV * (size_t)N * 4u;   // 134 MB
    const size_t w_bytes = (35*64 + 13*64) * sizeof(float);

    bool two_pass  = (ws_size >= packed_bytes + feats_bytes + w_bytes);
    bool packed_ok = (ws_size >= packed_bytes + w_bytes);

    uint32_t* tpk   = (uint32_t*)d_ws;
    uint32_t* feats = (uint32_t*)((char*)d_ws + packed_bytes);
    size_t w_off = packed_ok ? (packed_bytes + (two_pass ? feats_bytes : 0)) : 0;
    float* w1t = (float*)((char*)d_ws + w_off);
    float* w2n = w1t + 35 * 64;

    LevelParams P;
    P.hashed_mask = 0u;
    double pls = pow(128.0, 1.0 / 15.0);
    for (int l = 0; l < NLEV; ++l) {
        double sc = 16.0 * pow(pls, (double)l) - 1.0;
        P.scale[l] = (float)sc;
        uint32_t res = (uint32_t)(ceil(sc)) + 1u;
        P.res[l] = res;
        uint64_t r3 = (uint64_t)res * res * res;
        if (r3 > (uint64_t)TBL) P.hashed_mask |= (1u << l);
    }

    prep_weights<<<1, 128, 0, stream>>>(v1, g1, v2, g2, w1t, w2n);

    int chunks = (N + 255) / 256;
    if (two_pass) {
        pack_table<<<(n_entries + 255) / 256, 256, 0, stream>>>(
            (const float2*)table, tpk, n_entries);
        encode_level<<<chunks * NLEV, 256, 0, stream>>>(
            x, tpk, feats, N, chunks, P);
        mlp_kernel<<<chunks, 256, 0, stream>>>(
            x, feats, w1t, b1, w2n, b2, out, N);
    } else if (packed_ok) {
        pack_table<<<(n_entries + 255) / 256, 256, 0, stream>>>(
            (const float2*)table, tpk, n_entries);
        sdf_fused<1><<<chunks, 256, 0, stream>>>(
            x, (const void*)tpk, w1t, b1, w2n, b2, out, N, P);
    } else {
        sdf_fused<0><<<chunks, 256, 0, stream>>>(
            x, (const void*)table, w1t, b1, w2n, b2, out, N, P);
    }
}

// Round 4
// 993.491 us; speedup vs baseline: 1.6963x; 1.0259x over previous
//
#include <hip/hip_runtime.h>
#include <hip/hip_fp16.h>
#include <cstdint>
#include <cmath>

#define NLEV 16
#define NHASH 11          // levels 5..15 are hashed
#define NDENSE 5          // levels 0..4 are dense (tables total ~1.3 MB packed)
#define TBL (1u << 19)

struct LevelParams {
    float scale[NLEV];
    uint32_t res[NLEV];
    uint32_t hashed_mask;
};

// ---------------------------------------------------------------------------
// Prep 1: weight-norm both layers; transpose W1 to [35][64].
// ---------------------------------------------------------------------------
__global__ __launch_bounds__(128) void prep_weights(
    const float* __restrict__ v1, const float* __restrict__ g1,
    const float* __restrict__ v2, const float* __restrict__ g2,
    float* __restrict__ w1t, float* __restrict__ w2n)
{
    int t = threadIdx.x;
    if (t < 64) {
        float s = 0.f;
        #pragma unroll
        for (int k = 0; k < 35; ++k) { float v = v1[t*35 + k]; s += v*v; }
        float f = g1[t] / sqrtf(s);
        #pragma unroll
        for (int k = 0; k < 35; ++k) w1t[k*64 + t] = v1[t*35 + k] * f;
    } else if (t < 77) {
        int r = t - 64;
        float s = 0.f;
        #pragma unroll
        for (int k = 0; k < 64; ++k) { float v = v2[r*64 + k]; s += v*v; }
        float f = g2[r] / sqrtf(s);
        #pragma unroll
        for (int k = 0; k < 64; ++k) w2n[r*64 + k] = v2[r*64 + k] * f;
    }
}

// ---------------------------------------------------------------------------
// Prep 2: pack fp32 table [16*T][2] -> fp16x2 (one dword per entry).
// ---------------------------------------------------------------------------
__global__ __launch_bounds__(256) void pack_table(
    const float2* __restrict__ in, uint32_t* __restrict__ out, int n)
{
    int i = blockIdx.x * 256 + threadIdx.x;
    if (i < n) {
        float2 v = in[i];
        __half2 h = __floats2half2_rn(v.x, v.y);
        out[i] = *reinterpret_cast<uint32_t*>(&h);
    }
}

// ---------------------------------------------------------------------------
// Trilinear hashgrid lookup (packed fp16x2 table) for one (point, level).
// ---------------------------------------------------------------------------
__device__ __forceinline__ void encode_one(
    float u0, float u1, float u2, float s, uint32_t res, bool hashed,
    const uint32_t* __restrict__ tl, float& a0, float& a1)
{
    float px = u0 * s + 0.5f;
    float py = u1 * s + 0.5f;
    float pz = u2 * s + 0.5f;
    float fx = floorf(px), fy = floorf(py), fz = floorf(pz);
    float wx1 = px - fx, wy1 = py - fy, wz1 = pz - fz;
    float wx0 = 1.f - wx1, wy0 = 1.f - wy1, wz0 = 1.f - wz1;
    uint32_t cx = (uint32_t)fx, cy = (uint32_t)fy, cz = (uint32_t)fz;

    uint32_t ix0, ix1, iy0, iy1, iz0, iz1;
    if (hashed) {
        ix0 = cx;                 ix1 = cx + 1u;
        iy0 = cy * 2654435761u;   iy1 = (cy + 1u) * 2654435761u;
        iz0 = cz * 805459861u;    iz1 = (cz + 1u) * 805459861u;
    } else {
        ix0 = cx;                 ix1 = cx + 1u;
        iy0 = cy * res;           iy1 = iy0 + res;
        uint32_t rr = res * res;
        iz0 = cz * rr;            iz1 = iz0 + rr;
    }

    uint32_t idxs[8];
    #pragma unroll
    for (int c = 0; c < 8; ++c) {
        uint32_t jx = (c & 1) ? ix1 : ix0;
        uint32_t jy = (c & 2) ? iy1 : iy0;
        uint32_t jz = (c & 4) ? iz1 : iz0;
        idxs[c] = hashed ? ((jx ^ jy ^ jz) & (TBL - 1u)) : (jx + jy + jz);
    }
    uint32_t raw[8];
    #pragma unroll
    for (int c = 0; c < 8; ++c) raw[c] = tl[idxs[c]];

    float wxy00 = wx0*wy0, wxy10 = wx1*wy0, wxy01 = wx0*wy1, wxy11 = wx1*wy1;
    a0 = 0.f; a1 = 0.f;
    #pragma unroll
    for (int c = 0; c < 8; ++c) {
        float wxy = (c & 2) ? ((c & 1) ? wxy11 : wxy01)
                            : ((c & 1) ? wxy10 : wxy00);
        float w = wxy * ((c & 4) ? wz1 : wz0);
        __half2 hv = *reinterpret_cast<__half2*>(&raw[c]);
        float2 v = __half22float2(hv);
        a0 += w * v.x;
        a1 += w * v.y;
    }
}

// ---------------------------------------------------------------------------
// Pass A: encode the 11 HASHED levels only, level-major partitioned so the
// live level's 2 MB table is L2-resident. Writes half2 feats [li][N].
// ---------------------------------------------------------------------------
__global__ __launch_bounds__(256) void encode_hashed(
    const float* __restrict__ x, const uint32_t* __restrict__ tpk,
    uint32_t* __restrict__ feats, int N, int chunks_per_level, LevelParams P)
{
    int bid = blockIdx.x;
    int li = bid / chunks_per_level;           // 0..10
    int l = li + NDENSE;                       // 5..15
    int p = (bid - li * chunks_per_level) * 256 + threadIdx.x;
    if (p >= N) return;

    float x0 = x[3*(size_t)p + 0];
    float x1 = x[3*(size_t)p + 1];
    float x2 = x[3*(size_t)p + 2];
    float u0 = fminf(fmaxf(x0 + 0.5f, 0.f), 1.f);
    float u1 = fminf(fmaxf(x1 + 0.5f, 0.f), 1.f);
    float u2 = fminf(fmaxf(x2 + 0.5f, 0.f), 1.f);

    const uint32_t* tl = tpk + (size_t)l * TBL;
    float a0, a1;
    encode_one(u0, u1, u2, P.scale[l], P.res[l], true, tl, a0, a1);

    __half2 hv = __floats2half2_rn(a0, a1);
    feats[(size_t)li * N + p] = *reinterpret_cast<uint32_t*>(&hv);
}

// ---------------------------------------------------------------------------
// Pass B: dense levels 0..4 (1.3 MB packed tables, L2-resident everywhere)
// + MLP 35 -> softplus(100) -> 64 -> 13. Dense gathers overlap MLP FMAs.
// ---------------------------------------------------------------------------
__global__ __launch_bounds__(256) void mlp_dense(
    const float* __restrict__ x, const uint32_t* __restrict__ tpk,
    const uint32_t* __restrict__ feats,
    const float* __restrict__ w1t,   // [35][64]
    const float* __restrict__ b1,    // [64]
    const float* __restrict__ w2,    // [13][64]
    const float* __restrict__ b2,    // [13]
    float* __restrict__ out, int N, LevelParams P)
{
    int p = blockIdx.x * 256 + threadIdx.x;
    bool valid = (p < N);
    int pp = valid ? p : (N - 1);

    float x0 = x[3*(size_t)pp + 0];
    float x1 = x[3*(size_t)pp + 1];
    float x2 = x[3*(size_t)pp + 2];
    float u0 = fminf(fmaxf(x0 + 0.5f, 0.f), 1.f);
    float u1 = fminf(fmaxf(x1 + 0.5f, 0.f), 1.f);
    float u2 = fminf(fmaxf(x2 + 0.5f, 0.f), 1.f);

    // issue the 11 coalesced feat loads early
    uint32_t rf[NHASH];
    #pragma unroll
    for (int li = 0; li < NHASH; ++li) rf[li] = feats[(size_t)li * N + pp];

    // seed h with bias + xyz columns
    float h[64];
    #pragma unroll
    for (int j = 0; j < 64; ++j) {
        h[j] = b1[j] + x0 * w1t[0*64 + j] + x1 * w1t[1*64 + j] + x2 * w1t[2*64 + j];
    }

    // dense levels 0..4 inline
    #pragma unroll
    for (int l = 0; l < NDENSE; ++l) {
        const uint32_t* tl = tpk + (size_t)l * TBL;
        float a0, a1;
        encode_one(u0, u1, u2, P.scale[l], P.res[l], false, tl, a0, a1);
        const float* c0p = w1t + (3 + 2*l) * 64;
        const float* c1p = c0p + 64;
        #pragma unroll
        for (int j = 0; j < 64; ++j) h[j] += a0 * c0p[j] + a1 * c1p[j];
    }

    // hashed feats fold
    #pragma unroll
    for (int li = 0; li < NHASH; ++li) {
        __half2 hv = *reinterpret_cast<__half2*>(&rf[li]);
        float2 f = __half22float2(hv);
        int l = li + NDENSE;
        const float* c0p = w1t + (3 + 2*l) * 64;
        const float* c1p = c0p + 64;
        #pragma unroll
        for (int j = 0; j < 64; ++j) h[j] += f.x * c0p[j] + f.y * c1p[j];
    }

    // softplus(100*x)/100, numerically stable
    #pragma unroll
    for (int j = 0; j < 64; ++j) {
        float z = 100.f * h[j];
        float t = __expf(-fabsf(z));
        h[j] = (fmaxf(z, 0.f) + __logf(1.f + t)) * 0.01f;
    }

    float* op = out + (size_t)pp * 13;
    for (int o = 0; o < 13; ++o) {
        float a = b2[o];
        const float* wr = w2 + o * 64;
        #pragma unroll
        for (int k = 0; k < 64; ++k) a = fmaf(h[k], wr[k], a);
        if (valid) op[o] = a;
    }
}

// ---------------------------------------------------------------------------
// Fallback: fused kernel (used only if ws can't hold table+features).
// ---------------------------------------------------------------------------
template <int PACKED>
__global__ __launch_bounds__(256) void sdf_fused(
    const float* __restrict__ x, const void* __restrict__ table,
    const float* __restrict__ w1t, const float* __restrict__ b1,
    const float* __restrict__ w2, const float* __restrict__ b2,
    float* __restrict__ out, int N, LevelParams P)
{
    int i = blockIdx.x * 256 + threadIdx.x;
    bool valid = (i < N);
    int ii = valid ? i : (N - 1);

    float x0 = x[3*(size_t)ii + 0];
    float x1 = x[3*(size_t)ii + 1];
    float x2 = x[3*(size_t)ii + 2];
    float u0 = fminf(fmaxf(x0 + 0.5f, 0.f), 1.f);
    float u1 = fminf(fmaxf(x1 + 0.5f, 0.f), 1.f);
    float u2 = fminf(fmaxf(x2 + 0.5f, 0.f), 1.f);

    float h[64];
    #pragma unroll
    for (int j = 0; j < 64; ++j) {
        h[j] = b1[j] + x0 * w1t[0*64 + j] + x1 * w1t[1*64 + j] + x2 * w1t[2*64 + j];
    }

    for (int l = 0; l < NLEV; ++l) {
        bool hashed = (P.hashed_mask >> l) & 1u;
        float a0, a1;
        if (PACKED) {
            const uint32_t* tl = (const uint32_t*)table + (size_t)l * TBL;
            encode_one(u0, u1, u2, P.scale[l], P.res[l], hashed, tl, a0, a1);
        } else {
            const float* tl = (const float*)table + (size_t)l * (size_t)(TBL * 2u);
            float s = P.scale[l]; uint32_t res = P.res[l];
            float px = u0*s + 0.5f, py = u1*s + 0.5f, pz = u2*s + 0.5f;
            float fx = floorf(px), fy = floorf(py), fz = floorf(pz);
            float wx1 = px-fx, wy1 = py-fy, wz1 = pz-fz;
            float wx0 = 1.f-wx1, wy0 = 1.f-wy1, wz0 = 1.f-wz1;
            uint32_t cx = (uint32_t)fx, cy = (uint32_t)fy, cz = (uint32_t)fz;
            a0 = 0.f; a1 = 0.f;
            #pragma unroll
            for (int c = 0; c < 8; ++c) {
                uint32_t jx = cx + (c & 1);
                uint32_t jy = cy + ((c >> 1) & 1);
                uint32_t jz = cz + ((c >> 2) & 1);
                uint32_t idx = hashed
                    ? ((jx ^ (jy * 2654435761u) ^ (jz * 805459861u)) & (TBL - 1u))
                    : (jx + jy * res + jz * res * res);
                float w = ((c & 1) ? wx1 : wx0) * ((c & 2) ? wy1 : wy0)
                        * ((c & 4) ? wz1 : wz0);
                float2 v = *reinterpret_cast<const float2*>(tl + (size_t)idx * 2u);
                a0 += w * v.x; a1 += w * v.y;
            }
        }
        const float* c0p = w1t + (3 + 2*l) * 64;
        const float* c1p = c0p + 64;
        #pragma unroll
        for (int j = 0; j < 64; ++j) h[j] += a0 * c0p[j] + a1 * c1p[j];
    }

    #pragma unroll
    for (int j = 0; j < 64; ++j) {
        float z = 100.f * h[j];
        float t = __expf(-fabsf(z));
        h[j] = (fmaxf(z, 0.f) + __logf(1.f + t)) * 0.01f;
    }

    float* op = out + (size_t)ii * 13;
    for (int o = 0; o < 13; ++o) {
        float a = b2[o];
        const float* wr = w2 + o * 64;
        #pragma unroll
        for (int k = 0; k < 64; ++k) a += h[k] * wr[k];
        if (valid) op[o] = a;
    }
}

extern "C" void kernel_launch(void* const* d_in, const int* in_sizes, int n_in,
                              void* d_out, int out_size, void* d_ws, size_t ws_size,
                              hipStream_t stream)
{
    const float* x     = (const float*)d_in[0];
    const float* table = (const float*)d_in[1];
    const float* v1    = (const float*)d_in[2];
    const float* g1    = (const float*)d_in[3];
    const float* b1    = (const float*)d_in[4];
    const float* v2    = (const float*)d_in[5];
    const float* g2    = (const float*)d_in[6];
    const float* b2    = (const float*)d_in[7];
    float* out = (float*)d_out;
    int N = in_sizes[0] / 3;

    const int n_entries = NLEV * (int)TBL;
    const size_t packed_bytes = (size_t)n_entries * 4u;            // 32 MB
    const size_t feats_bytes  = (size_t)NHASH * (size_t)N * 4u;    // 92 MB
    const size_t w_bytes = (35*64 + 13*64) * sizeof(float);

    bool two_pass  = (ws_size >= packed_bytes + feats_bytes + w_bytes);
    bool packed_ok = (ws_size >= packed_bytes + w_bytes);

    uint32_t* tpk   = (uint32_t*)d_ws;
    uint32_t* feats = (uint32_t*)((char*)d_ws + packed_bytes);
    size_t w_off = packed_ok ? (packed_bytes + (two_pass ? feats_bytes : 0)) : 0;
    float* w1t = (float*)((char*)d_ws + w_off);
    float* w2n = w1t + 35 * 64;

    LevelParams P;
    P.hashed_mask = 0u;
    double pls = pow(128.0, 1.0 / 15.0);
    for (int l = 0; l < NLEV; ++l) {
        double sc = 16.0 * pow(pls, (double)l) - 1.0;
        P.scale[l] = (float)sc;
        uint32_t res = (uint32_t)(ceil(sc)) + 1u;
        P.res[l] = res;
        uint64_t r3 = (uint64_t)res * res * res;
        if (r3 > (uint64_t)TBL) P.hashed_mask |= (1u << l);
    }

    prep_weights<<<1, 128, 0, stream>>>(v1, g1, v2, g2, w1t, w2n);

    int chunks = (N + 255) / 256;
    if (two_pass) {
        pack_table<<<(n_entries + 255) / 256, 256, 0, stream>>>(
            (const float2*)table, tpk, n_entries);
        encode_hashed<<<chunks * NHASH, 256, 0, stream>>>(
            x, tpk, feats, N, chunks, P);
        mlp_dense<<<chunks, 256, 0, stream>>>(
            x, tpk, feats, w1t, b1, w2n, b2, out, N, P);
    } else if (packed_ok) {
        pack_table<<<(n_entries + 255) / 256, 256, 0, stream>>>(
            (const float2*)table, tpk, n_entries);
        sdf_fused<1><<<chunks, 256, 0, stream>>>(
            x, (const void*)tpk, w1t, b1, w2n, b2, out, N, P);
    } else {
        sdf_fused<0><<<chunks, 256, 0, stream>>>(
            x, (const void*)table, w1t, b1, w2n, b2, out, N, P);
    }
}

// Round 5
// 780.517 us; speedup vs baseline: 2.1592x; 1.2729x over previous
//
#include <hip/hip_runtime.h>
#include <hip/hip_fp16.h>
#include <cstdint>
#include <cmath>

#define NLEV 16
#define NHASH 11          // levels 5..15 are hashed
#define NDENSE 5          // levels 0..4 are dense
#define TBL (1u << 19)

struct LevelParams {
    float scale[NLEV];
    uint32_t res[NLEV];
    uint32_t hashed_mask;
};

// ---------------------------------------------------------------------------
// Prep 1: weight-norm both layers; transpose W1 to [35][64].
// ---------------------------------------------------------------------------
__global__ __launch_bounds__(128) void prep_weights(
    const float* __restrict__ v1, const float* __restrict__ g1,
    const float* __restrict__ v2, const float* __restrict__ g2,
    float* __restrict__ w1t, float* __restrict__ w2n)
{
    int t = threadIdx.x;
    if (t < 64) {
        float s = 0.f;
        #pragma unroll
        for (int k = 0; k < 35; ++k) { float v = v1[t*35 + k]; s += v*v; }
        float f = g1[t] / sqrtf(s);
        #pragma unroll
        for (int k = 0; k < 35; ++k) w1t[k*64 + t] = v1[t*35 + k] * f;
    } else if (t < 77) {
        int r = t - 64;
        float s = 0.f;
        #pragma unroll
        for (int k = 0; k < 64; ++k) { float v = v2[r*64 + k]; s += v*v; }
        float f = g2[r] / sqrtf(s);
        #pragma unroll
        for (int k = 0; k < 64; ++k) w2n[r*64 + k] = v2[r*64 + k] * f;
    }
}

// ---------------------------------------------------------------------------
// Prep 2: pack fp32 table [16*T][2] -> fp16x2 (one dword per entry).
// ---------------------------------------------------------------------------
__global__ __launch_bounds__(256) void pack_table(
    const float2* __restrict__ in, uint32_t* __restrict__ out, int n)
{
    int i = blockIdx.x * 256 + threadIdx.x;
    if (i < n) {
        float2 v = in[i];
        __half2 h = __floats2half2_rn(v.x, v.y);
        out[i] = *reinterpret_cast<uint32_t*>(&h);
    }
}

// ---------------------------------------------------------------------------
// Generic trilinear lookup (packed table) — used for dense levels + fallback.
// ---------------------------------------------------------------------------
__device__ __forceinline__ void encode_one(
    float u0, float u1, float u2, float s, uint32_t res, bool hashed,
    const uint32_t* __restrict__ tl, float& a0, float& a1)
{
    float px = u0 * s + 0.5f;
    float py = u1 * s + 0.5f;
    float pz = u2 * s + 0.5f;
    float fx = floorf(px), fy = floorf(py), fz = floorf(pz);
    float wx1 = px - fx, wy1 = py - fy, wz1 = pz - fz;
    float wx0 = 1.f - wx1, wy0 = 1.f - wy1, wz0 = 1.f - wz1;
    uint32_t cx = (uint32_t)fx, cy = (uint32_t)fy, cz = (uint32_t)fz;

    uint32_t ix0, ix1, iy0, iy1, iz0, iz1;
    if (hashed) {
        ix0 = cx;                 ix1 = cx + 1u;
        iy0 = cy * 2654435761u;   iy1 = (cy + 1u) * 2654435761u;
        iz0 = cz * 805459861u;    iz1 = (cz + 1u) * 805459861u;
    } else {
        ix0 = cx;                 ix1 = cx + 1u;
        iy0 = cy * res;           iy1 = iy0 + res;
        uint32_t rr = res * res;
        iz0 = cz * rr;            iz1 = iz0 + rr;
    }

    uint32_t idxs[8];
    #pragma unroll
    for (int c = 0; c < 8; ++c) {
        uint32_t jx = (c & 1) ? ix1 : ix0;
        uint32_t jy = (c & 2) ? iy1 : iy0;
        uint32_t jz = (c & 4) ? iz1 : iz0;
        idxs[c] = hashed ? ((jx ^ jy ^ jz) & (TBL - 1u)) : (jx + jy + jz);
    }
    uint32_t raw[8];
    #pragma unroll
    for (int c = 0; c < 8; ++c) raw[c] = tl[idxs[c]];

    float wxy00 = wx0*wy0, wxy10 = wx1*wy0, wxy01 = wx0*wy1, wxy11 = wx1*wy1;
    a0 = 0.f; a1 = 0.f;
    #pragma unroll
    for (int c = 0; c < 8; ++c) {
        float wxy = (c & 2) ? ((c & 1) ? wxy11 : wxy01)
                            : ((c & 1) ? wxy10 : wxy00);
        float w = wxy * ((c & 4) ? wz1 : wz0);
        __half2 hv = *reinterpret_cast<__half2*>(&raw[c]);
        float2 v = __half22float2(hv);
        a0 += w * v.x;
        a1 += w * v.y;
    }
}

// ---------------------------------------------------------------------------
// Pass A: hashed levels, level-major partitioned (2 MB table L2-resident).
// 2 points per thread for MLP-depth; even-cx corner pairs fetched as one
// aligned dwordx2 (PRIMES[0]==1 => x-neighbors are v and v^1). Parity select
// deferred to the fold so no waitcnt splits the two points' load batches.
// ---------------------------------------------------------------------------
__global__ __launch_bounds__(256) void encode_hashed(
    const float* __restrict__ x, const uint32_t* __restrict__ tpk,
    uint32_t* __restrict__ feats, int N, int chunks_per_level, LevelParams P)
{
    int bid = blockIdx.x;
    int li = bid / chunks_per_level;           // 0..NHASH-1
    int l = li + NDENSE;                       // 5..15
    int base = (bid - li * chunks_per_level) * 512 + threadIdx.x;
    const uint32_t* tl = tpk + (size_t)l * TBL;
    float s = P.scale[l];

    int p[2] = { base, base + 256 };

    uint2 Q[2][4];
    uint32_t par[2];
    float wx0[2], wx1[2], wyz[2][4];

    #pragma unroll
    for (int t = 0; t < 2; ++t) {
        int pp = (p[t] < N) ? p[t] : (N - 1);
        float x0 = __builtin_nontemporal_load(&x[3*(size_t)pp + 0]);
        float x1 = __builtin_nontemporal_load(&x[3*(size_t)pp + 1]);
        float x2 = __builtin_nontemporal_load(&x[3*(size_t)pp + 2]);
        float u0 = fminf(fmaxf(x0 + 0.5f, 0.f), 1.f);
        float u1 = fminf(fmaxf(x1 + 0.5f, 0.f), 1.f);
        float u2 = fminf(fmaxf(x2 + 0.5f, 0.f), 1.f);

        float px = u0 * s + 0.5f;
        float py = u1 * s + 0.5f;
        float pz = u2 * s + 0.5f;
        float fx = floorf(px), fy = floorf(py), fz = floorf(pz);
        float a1f = px - fx, b1f = py - fy, c1f = pz - fz;
        wx1[t] = a1f; wx0[t] = 1.f - a1f;
        float wy0 = 1.f - b1f, wz0 = 1.f - c1f;
        uint32_t cx = (uint32_t)fx, cy = (uint32_t)fy, cz = (uint32_t)fz;

        wyz[t][0] = wy0 * wz0;
        wyz[t][1] = b1f * wz0;
        wyz[t][2] = wy0 * c1f;
        wyz[t][3] = b1f * c1f;

        uint32_t hy0 = cy * 2654435761u, hy1 = (cy + 1u) * 2654435761u;
        uint32_t hz0 = cz * 805459861u,  hz1 = (cz + 1u) * 805459861u;
        uint32_t r[4] = { hy0 ^ hz0, hy1 ^ hz0, hy0 ^ hz1, hy1 ^ hz1 };

        par[t] = 0u;
        if (!(cx & 1u)) {
            // even cx: {cx^r, (cx+1)^r} = {v, v^1} -> one aligned 8B load
            #pragma unroll
            for (int k = 0; k < 4; ++k) {
                uint32_t v0 = (cx ^ r[k]) & (TBL - 1u);
                Q[t][k] = *reinterpret_cast<const uint2*>(tl + (v0 & ~1u));
                par[t] |= (v0 & 1u) << k;
            }
        } else {
            #pragma unroll
            for (int k = 0; k < 4; ++k) {
                uint32_t v0 = (cx ^ r[k]) & (TBL - 1u);
                uint32_t v1 = ((cx + 1u) ^ r[k]) & (TBL - 1u);
                Q[t][k].x = tl[v0];
                Q[t][k].y = tl[v1];
            }
        }
    }

    #pragma unroll
    for (int t = 0; t < 2; ++t) {
        float a0 = 0.f, a1 = 0.f;
        #pragma unroll
        for (int k = 0; k < 4; ++k) {
            uint32_t swap = (par[t] >> k) & 1u;
            uint32_t b0 = swap ? Q[t][k].y : Q[t][k].x;   // corner x=0
            uint32_t b1 = swap ? Q[t][k].x : Q[t][k].y;   // corner x=1
            __half2 h0 = *reinterpret_cast<__half2*>(&b0);
            __half2 h1 = *reinterpret_cast<__half2*>(&b1);
            float2 c0 = __half22float2(h0);
            float2 c1 = __half22float2(h1);
            a0 += wyz[t][k] * (wx0[t] * c0.x + wx1[t] * c1.x);
            a1 += wyz[t][k] * (wx0[t] * c0.y + wx1[t] * c1.y);
        }
        __half2 hv = __floats2half2_rn(a0, a1);
        if (p[t] < N) {
            __builtin_nontemporal_store(*reinterpret_cast<uint32_t*>(&hv),
                                        &feats[(size_t)li * N + p[t]]);
        }
    }
}

// ---------------------------------------------------------------------------
// Pass B: dense levels 0..4 inline (~1.3 MB packed tables, L2-resident
// everywhere) + MLP 35 -> softplus(100) -> 64 -> 13.
// ---------------------------------------------------------------------------
__global__ __launch_bounds__(256) void mlp_dense(
    const float* __restrict__ x, const uint32_t* __restrict__ tpk,
    const uint32_t* __restrict__ feats,
    const float* __restrict__ w1t,   // [35][64]
    const float* __restrict__ b1,    // [64]
    const float* __restrict__ w2,    // [13][64]
    const float* __restrict__ b2,    // [13]
    float* __restrict__ out, int N, LevelParams P)
{
    int p = blockIdx.x * 256 + threadIdx.x;
    bool valid = (p < N);
    int pp = valid ? p : (N - 1);

    float x0 = x[3*(size_t)pp + 0];
    float x1 = x[3*(size_t)pp + 1];
    float x2 = x[3*(size_t)pp + 2];
    float u0 = fminf(fmaxf(x0 + 0.5f, 0.f), 1.f);
    float u1 = fminf(fmaxf(x1 + 0.5f, 0.f), 1.f);
    float u2 = fminf(fmaxf(x2 + 0.5f, 0.f), 1.f);

    uint32_t rf[NHASH];
    #pragma unroll
    for (int li = 0; li < NHASH; ++li) rf[li] = feats[(size_t)li * N + pp];

    float h[64];
    #pragma unroll
    for (int j = 0; j < 64; ++j) {
        h[j] = b1[j] + x0 * w1t[0*64 + j] + x1 * w1t[1*64 + j] + x2 * w1t[2*64 + j];
    }

    #pragma unroll
    for (int l = 0; l < NDENSE; ++l) {
        const uint32_t* tl = tpk + (size_t)l * TBL;
        float a0, a1;
        encode_one(u0, u1, u2, P.scale[l], P.res[l], false, tl, a0, a1);
        const float* c0p = w1t + (3 + 2*l) * 64;
        const float* c1p = c0p + 64;
        #pragma unroll
        for (int j = 0; j < 64; ++j) h[j] += a0 * c0p[j] + a1 * c1p[j];
    }

    #pragma unroll
    for (int li = 0; li < NHASH; ++li) {
        __half2 hv = *reinterpret_cast<__half2*>(&rf[li]);
        float2 f = __half22float2(hv);
        int l = li + NDENSE;
        const float* c0p = w1t + (3 + 2*l) * 64;
        const float* c1p = c0p + 64;
        #pragma unroll
        for (int j = 0; j < 64; ++j) h[j] += f.x * c0p[j] + f.y * c1p[j];
    }

    #pragma unroll
    for (int j = 0; j < 64; ++j) {
        float z = 100.f * h[j];
        float t = __expf(-fabsf(z));
        h[j] = (fmaxf(z, 0.f) + __logf(1.f + t)) * 0.01f;
    }

    float* op = out + (size_t)pp * 13;
    for (int o = 0; o < 13; ++o) {
        float a = b2[o];
        const float* wr = w2 + o * 64;
        #pragma unroll
        for (int k = 0; k < 64; ++k) a = fmaf(h[k], wr[k], a);
        if (valid) op[o] = a;
    }
}

// ---------------------------------------------------------------------------
// Fallback: fused kernel (used only if ws can't hold table+features).
// ---------------------------------------------------------------------------
template <int PACKED>
__global__ __launch_bounds__(256) void sdf_fused(
    const float* __restrict__ x, const void* __restrict__ table,
    const float* __restrict__ w1t, const float* __restrict__ b1,
    const float* __restrict__ w2, const float* __restrict__ b2,
    float* __restrict__ out, int N, LevelParams P)
{
    int i = blockIdx.x * 256 + threadIdx.x;
    bool valid = (i < N);
    int ii = valid ? i : (N - 1);

    float x0 = x[3*(size_t)ii + 0];
    float x1 = x[3*(size_t)ii + 1];
    float x2 = x[3*(size_t)ii + 2];
    float u0 = fminf(fmaxf(x0 + 0.5f, 0.f), 1.f);
    float u1 = fminf(fmaxf(x1 + 0.5f, 0.f), 1.f);
    float u2 = fminf(fmaxf(x2 + 0.5f, 0.f), 1.f);

    float h[64];
    #pragma unroll
    for (int j = 0; j < 64; ++j) {
        h[j] = b1[j] + x0 * w1t[0*64 + j] + x1 * w1t[1*64 + j] + x2 * w1t[2*64 + j];
    }

    for (int l = 0; l < NLEV; ++l) {
        bool hashed = (P.hashed_mask >> l) & 1u;
        float a0, a1;
        if (PACKED) {
            const uint32_t* tl = (const uint32_t*)table + (size_t)l * TBL;
            encode_one(u0, u1, u2, P.scale[l], P.res[l], hashed, tl, a0, a1);
        } else {
            const float* tl = (const float*)table + (size_t)l * (size_t)(TBL * 2u);
            float s = P.scale[l]; uint32_t res = P.res[l];
            float px = u0*s + 0.5f, py = u1*s + 0.5f, pz = u2*s + 0.5f;
            float fx = floorf(px), fy = floorf(py), fz = floorf(pz);
            float wx1 = px-fx, wy1 = py-fy, wz1 = pz-fz;
            float wx0 = 1.f-wx1, wy0 = 1.f-wy1, wz0 = 1.f-wz1;
            uint32_t cx = (uint32_t)fx, cy = (uint32_t)fy, cz = (uint32_t)fz;
            a0 = 0.f; a1 = 0.f;
            #pragma unroll
            for (int c = 0; c < 8; ++c) {
                uint32_t jx = cx + (c & 1);
                uint32_t jy = cy + ((c >> 1) & 1);
                uint32_t jz = cz + ((c >> 2) & 1);
                uint32_t idx = hashed
                    ? ((jx ^ (jy * 2654435761u) ^ (jz * 805459861u)) & (TBL - 1u))
                    : (jx + jy * res + jz * res * res);
                float w = ((c & 1) ? wx1 : wx0) * ((c & 2) ? wy1 : wy0)
                        * ((c & 4) ? wz1 : wz0);
                float2 v = *reinterpret_cast<const float2*>(tl + (size_t)idx * 2u);
                a0 += w * v.x; a1 += w * v.y;
            }
        }
        const float* c0p = w1t + (3 + 2*l) * 64;
        const float* c1p = c0p + 64;
        #pragma unroll
        for (int j = 0; j < 64; ++j) h[j] += a0 * c0p[j] + a1 * c1p[j];
    }

    #pragma unroll
    for (int j = 0; j < 64; ++j) {
        float z = 100.f * h[j];
        float t = __expf(-fabsf(z));
        h[j] = (fmaxf(z, 0.f) + __logf(1.f + t)) * 0.01f;
    }

    float* op = out + (size_t)ii * 13;
    for (int o = 0; o < 13; ++o) {
        float a = b2[o];
        const float* wr = w2 + o * 64;
        #pragma unroll
        for (int k = 0; k < 64; ++k) a += h[k] * wr[k];
        if (valid) op[o] = a;
    }
}

extern "C" void kernel_launch(void* const* d_in, const int* in_sizes, int n_in,
                              void* d_out, int out_size, void* d_ws, size_t ws_size,
                              hipStream_t stream)
{
    const float* x     = (const float*)d_in[0];
    const float* table = (const float*)d_in[1];
    const float* v1    = (const float*)d_in[2];
    const float* g1    = (const float*)d_in[3];
    const float* b1    = (const float*)d_in[4];
    const float* v2    = (const float*)d_in[5];
    const float* g2    = (const float*)d_in[6];
    const float* b2    = (const float*)d_in[7];
    float* out = (float*)d_out;
    int N = in_sizes[0] / 3;

    const int n_entries = NLEV * (int)TBL;
    const size_t packed_bytes = (size_t)n_entries * 4u;            // 32 MB
    const size_t feats_bytes  = (size_t)NHASH * (size_t)N * 4u;    // 92 MB
    const size_t w_bytes = (35*64 + 13*64) * sizeof(float);

    bool two_pass  = (ws_size >= packed_bytes + feats_bytes + w_bytes);
    bool packed_ok = (ws_size >= packed_bytes + w_bytes);

    uint32_t* tpk   = (uint32_t*)d_ws;
    uint32_t* feats = (uint32_t*)((char*)d_ws + packed_bytes);
    size_t w_off = packed_ok ? (packed_bytes + (two_pass ? feats_bytes : 0)) : 0;
    float* w1t = (float*)((char*)d_ws + w_off);
    float* w2n = w1t + 35 * 64;

    LevelParams P;
    P.hashed_mask = 0u;
    double pls = pow(128.0, 1.0 / 15.0);
    for (int l = 0; l < NLEV; ++l) {
        double sc = 16.0 * pow(pls, (double)l) - 1.0;
        P.scale[l] = (float)sc;
        uint32_t res = (uint32_t)(ceil(sc)) + 1u;
        P.res[l] = res;
        uint64_t r3 = (uint64_t)res * res * res;
        if (r3 > (uint64_t)TBL) P.hashed_mask |= (1u << l);
    }

    prep_weights<<<1, 128, 0, stream>>>(v1, g1, v2, g2, w1t, w2n);

    int chunks = (N + 255) / 256;
    if (two_pass) {
        pack_table<<<(n_entries + 255) / 256, 256, 0, stream>>>(
            (const float2*)table, tpk, n_entries);
        int chunks2 = (N + 511) / 512;
        encode_hashed<<<chunks2 * NHASH, 256, 0, stream>>>(
            x, tpk, feats, N, chunks2, P);
        mlp_dense<<<chunks, 256, 0, stream>>>(
            x, tpk, feats, w1t, b1, w2n, b2, out, N, P);
    } else if (packed_ok) {
        pack_table<<<(n_entries + 255) / 256, 256, 0, stream>>>(
            (const float2*)table, tpk, n_entries);
        sdf_fused<1><<<chunks, 256, 0, stream>>>(
            x, (const void*)tpk, w1t, b1, w2n, b2, out, N, P);
    } else {
        sdf_fused<0><<<chunks, 256, 0, stream>>>(
            x, (const void*)table, w1t, b1, w2n, b2, out, N, P);
    }
}